// Round 2
// baseline (131.718 us; speedup 1.0000x reference)
//
#include <hip/hip_runtime.h>

#define NB 64
#define NI 1024
#define NO 1024
#define IROWS (NI + 1)
#define S_SPLIT 32
#define TJ 64

__device__ __forceinline__ float fast_exp2(float x) { return __builtin_amdgcn_exp2f(x); }
__device__ __forceinline__ float fast_log2(float x) { return __builtin_amdgcn_logf(x); }

// ---------------- Pass 1: max|W| over {w_pos, w_neg, b_pos, b_neg} ----------------
__global__ __launch_bounds__(256) void maxabs_kernel(
    const float* __restrict__ wp, const float* __restrict__ wn,
    const float* __restrict__ bp, const float* __restrict__ bn,
    unsigned* __restrict__ maxbits)
{
    int tid = blockIdx.x * blockDim.x + threadIdx.x;
    int stride = gridDim.x * blockDim.x;
    float m = 0.0f;
    const int NW = NI * NO;
    for (int idx = tid; idx < NW; idx += stride) {
        m = fmaxf(m, fabsf(wp[idx]));
        m = fmaxf(m, fabsf(wn[idx]));
    }
    for (int idx = tid; idx < NO; idx += stride) {
        m = fmaxf(m, fabsf(bp[idx]));
        m = fmaxf(m, fabsf(bn[idx]));
    }
    #pragma unroll
    for (int off = 32; off > 0; off >>= 1)
        m = fmaxf(m, __shfl_xor(m, off));
    if ((threadIdx.x & 63) == 0)
        atomicMax(maxbits, __float_as_uint(m));   // all values >= 0: uint order == float order
}

// ---------------- Pass 2: main compute ----------------
// Block: 256 threads = 64 j-pairs (tx) x 4 b-groups (ty); each thread owns 16 b rows.
// Grid: (NO/TJ) j-tiles x S_SPLIT i-chunks. Partial sums atomicAdd'ed into zeroed y.
__global__ __launch_bounds__(256) void memristor_main(
    const float* __restrict__ x,
    const float* __restrict__ w_pos, const float* __restrict__ w_neg,
    const float* __restrict__ b_pos, const float* __restrict__ b_neg,
    const float* __restrict__ n_param,
    const unsigned* __restrict__ maxbits,
    float* __restrict__ y)
{
    __shared__ float2 LS[NB][33];   // [b][local_i] : (L = log2(2|x|), s = sign)

    const float maxw = __uint_as_float(*maxbits);
    const float k_G = 0.9f / maxw;                 // (G_MAX - G_MIN)/max_w
    const float out_scale = 0.25f / (0.5f * k_G);  // V_REF / (k_V * k_G)

    const int jt = blockIdx.x;
    const int s  = blockIdx.y;
    const int base  = IROWS / S_SPLIT;   // 32
    const int extra = IROWS % S_SPLIT;   // 1
    const int i0  = s * base + min(s, extra);
    const int len = base + (s < extra ? 1 : 0);

    const int tid = threadIdx.x;

    // ---- stage L, sign for this i-chunk (all 64 b) ----
    {
        const int li = tid & 63;
        if (li < len) {
            const int gi = i0 + li;
            #pragma unroll 4
            for (int bb = tid >> 6; bb < NB; bb += 4) {
                float v  = (gi < NI) ? x[bb * NI + gi] : 1.0f;   // appended ones column
                float sg = (v > 0.0f) ? 1.0f : ((v < 0.0f) ? -1.0f : 0.0f);
                float L  = fast_log2(fabsf(v)) + 1.0f;           // log2(2|v|) ; v=0 -> -inf (ok)
                LS[bb][li] = make_float2(L, sg);
            }
        }
    }
    __syncthreads();

    const int tx = tid & 63;
    const int ty = tid >> 6;
    const int jp = jt * TJ + tx;    // global j-pair (output column)

    float acc[16];
    #pragma unroll
    for (int k = 0; k < 16; ++k) acc[k] = 0.0f;

    const int reg_len = min(len, NI - i0);   // rows taken from w matrices (gi < 1024)
    for (int ii = 0; ii < reg_len; ++ii) {
        const int gi = i0 + ii;
        const float  wpv = w_pos[gi * NO + jp];
        const float  wnv = w_neg[gi * NO + jp];
        const float2 n2  = reinterpret_cast<const float2*>(n_param + (size_t)gi * 2 * NO)[jp];
        const float Gp = fmaf(k_G, wpv, 0.1f);
        const float Gn = fmaf(k_G, wnv, 0.1f);
        const float ep = fast_log2(n2.x);
        const float en = fast_log2(n2.y);
        #pragma unroll
        for (int k = 0; k < 16; ++k) {
            const float2 ls = LS[ty * 16 + k][ii];   // wave-uniform broadcast read
            const float Pp = fast_exp2(ep * ls.x);
            const float Pn = fast_exp2(en * ls.x);
            const float u  = fmaf(Gn, -Pn, Gp * Pp);
            acc[k] = fmaf(ls.y, u, acc[k]);
        }
    }

    if (i0 + len > NI) {   // bias row (gi == NI) lives at local index len-1
        const int ii = len - 1;
        const float  wpv = b_pos[jp];
        const float  wnv = b_neg[jp];
        const float2 n2  = reinterpret_cast<const float2*>(n_param + (size_t)NI * 2 * NO)[jp];
        const float Gp = fmaf(k_G, wpv, 0.1f);
        const float Gn = fmaf(k_G, wnv, 0.1f);
        const float ep = fast_log2(n2.x);
        const float en = fast_log2(n2.y);
        #pragma unroll
        for (int k = 0; k < 16; ++k) {
            const float2 ls = LS[ty * 16 + k][ii];
            const float Pp = fast_exp2(ep * ls.x);
            const float Pn = fast_exp2(en * ls.x);
            const float u  = fmaf(Gn, -Pn, Gp * Pp);
            acc[k] = fmaf(ls.y, u, acc[k]);
        }
    }

    #pragma unroll
    for (int k = 0; k < 16; ++k)
        atomicAdd(&y[(ty * 16 + k) * NO + jp], acc[k] * out_scale);
}

extern "C" void kernel_launch(void* const* d_in, const int* in_sizes, int n_in,
                              void* d_out, int out_size, void* d_ws, size_t ws_size,
                              hipStream_t stream)
{
    const float* x     = (const float*)d_in[0];
    const float* w_pos = (const float*)d_in[1];
    const float* w_neg = (const float*)d_in[2];
    const float* b_pos = (const float*)d_in[3];
    const float* b_neg = (const float*)d_in[4];
    const float* n_par = (const float*)d_in[5];
    float*    y        = (float*)d_out;
    unsigned* maxbits  = (unsigned*)d_ws;

    (void)hipMemsetAsync(maxbits, 0, sizeof(unsigned), stream);
    (void)hipMemsetAsync(y, 0, (size_t)NB * NO * sizeof(float), stream);

    maxabs_kernel<<<256, 256, 0, stream>>>(w_pos, w_neg, b_pos, b_neg, maxbits);

    dim3 grid(NO / TJ, S_SPLIT);
    memristor_main<<<grid, 256, 0, stream>>>(x, w_pos, w_neg, b_pos, b_neg, n_par,
                                             maxbits, y);
}

// Round 3
// 129.970 us; speedup vs baseline: 1.0134x; 1.0134x over previous
//
#include <hip/hip_runtime.h>

#define NB 64
#define NI 1024
#define NO 1024
#define IROWS (NI + 1)
#define S_SPLIT 32
#define TJ 64
#define NOUT (NB * NO)   // 65536 outputs

__device__ __forceinline__ float fast_exp2(float x) { return __builtin_amdgcn_exp2f(x); }
__device__ __forceinline__ float fast_log2(float x) { return __builtin_amdgcn_logf(x); }

// ---------------- Pass 1: max|W| over {w_pos, w_neg, b_pos, b_neg} ----------------
__global__ __launch_bounds__(256) void maxabs_kernel(
    const float* __restrict__ wp, const float* __restrict__ wn,
    const float* __restrict__ bp, const float* __restrict__ bn,
    unsigned* __restrict__ maxbits)
{
    int tid = blockIdx.x * blockDim.x + threadIdx.x;
    int stride = gridDim.x * blockDim.x;
    float m = 0.0f;
    const int NW = NI * NO;
    for (int idx = tid; idx < NW; idx += stride) {
        m = fmaxf(m, fabsf(wp[idx]));
        m = fmaxf(m, fabsf(wn[idx]));
    }
    for (int idx = tid; idx < NO; idx += stride) {
        m = fmaxf(m, fabsf(bp[idx]));
        m = fmaxf(m, fabsf(bn[idx]));
    }
    #pragma unroll
    for (int off = 32; off > 0; off >>= 1)
        m = fmaxf(m, __shfl_xor(m, off));
    if ((threadIdx.x & 63) == 0)
        atomicMax(maxbits, __float_as_uint(m));   // all values >= 0: uint order == float order
}

// ---------------- Pass 2: main compute (atomic-free, partials to ws) ----------------
// Block: 256 threads = 64 j-pairs (tx) x 4 b-groups (ty); each thread owns 16 b rows.
// Grid: (NO/TJ) j-tiles x S_SPLIT i-chunks. Partials stored to ws[s][b][j].
__global__ __launch_bounds__(256) void memristor_main(
    const float* __restrict__ x,
    const float* __restrict__ w_pos, const float* __restrict__ w_neg,
    const float* __restrict__ b_pos, const float* __restrict__ b_neg,
    const float* __restrict__ n_param,
    const unsigned* __restrict__ maxbits,
    float* __restrict__ partial)
{
    __shared__ float2 LS[NB][33];   // [b][local_i] : (L = log2(2|x|), s = sign)

    const float maxw = __uint_as_float(*maxbits);
    const float k_G = 0.9f / maxw;                 // (G_MAX - G_MIN)/max_w

    const int jt = blockIdx.x;
    const int s  = blockIdx.y;
    const int base  = IROWS / S_SPLIT;   // 32
    const int extra = IROWS % S_SPLIT;   // 1
    const int i0  = s * base + min(s, extra);
    const int len = base + (s < extra ? 1 : 0);

    const int tid = threadIdx.x;

    // ---- stage L, sign for this i-chunk (all 64 b) ----
    {
        const int li = tid & 63;
        if (li < len) {
            const int gi = i0 + li;
            #pragma unroll 4
            for (int bb = tid >> 6; bb < NB; bb += 4) {
                float v  = (gi < NI) ? x[bb * NI + gi] : 1.0f;   // appended ones column
                float sg = (v > 0.0f) ? 1.0f : ((v < 0.0f) ? -1.0f : 0.0f);
                float L  = fast_log2(fabsf(v)) + 1.0f;           // log2(2|v|) ; v=0 -> -inf (ok)
                LS[bb][li] = make_float2(L, sg);
            }
        }
    }
    __syncthreads();

    const int tx = tid & 63;
    const int ty = tid >> 6;
    const int jp = jt * TJ + tx;    // global j-pair (output column)

    float acc[16];
    #pragma unroll
    for (int k = 0; k < 16; ++k) acc[k] = 0.0f;

    const int reg_len = min(len, NI - i0);   // rows taken from w matrices (gi < 1024)
    for (int ii = 0; ii < reg_len; ++ii) {
        const int gi = i0 + ii;
        const float  wpv = w_pos[gi * NO + jp];
        const float  wnv = w_neg[gi * NO + jp];
        const float2 n2  = reinterpret_cast<const float2*>(n_param + (size_t)gi * 2 * NO)[jp];
        const float Gp = fmaf(k_G, wpv, 0.1f);
        const float Gn = fmaf(k_G, wnv, 0.1f);
        const float ep = fast_log2(n2.x);
        const float en = fast_log2(n2.y);
        #pragma unroll
        for (int k = 0; k < 16; ++k) {
            const float2 ls = LS[ty * 16 + k][ii];   // wave-uniform broadcast read
            const float Pp = fast_exp2(ep * ls.x);
            const float Pn = fast_exp2(en * ls.x);
            const float u  = fmaf(Gn, -Pn, Gp * Pp);
            acc[k] = fmaf(ls.y, u, acc[k]);
        }
    }

    if (i0 + len > NI) {   // bias row (gi == NI) lives at local index len-1
        const int ii = len - 1;
        const float  wpv = b_pos[jp];
        const float  wnv = b_neg[jp];
        const float2 n2  = reinterpret_cast<const float2*>(n_param + (size_t)NI * 2 * NO)[jp];
        const float Gp = fmaf(k_G, wpv, 0.1f);
        const float Gn = fmaf(k_G, wnv, 0.1f);
        const float ep = fast_log2(n2.x);
        const float en = fast_log2(n2.y);
        #pragma unroll
        for (int k = 0; k < 16; ++k) {
            const float2 ls = LS[ty * 16 + k][ii];
            const float Pp = fast_exp2(ep * ls.x);
            const float Pn = fast_exp2(en * ls.x);
            const float u  = fmaf(Gn, -Pn, Gp * Pp);
            acc[k] = fmaf(ls.y, u, acc[k]);
        }
    }

    // coalesced plain stores: partial[s][b][jp]
    float* slice = partial + (size_t)s * NOUT;
    #pragma unroll
    for (int k = 0; k < 16; ++k)
        slice[(ty * 16 + k) * NO + jp] = acc[k];
}

// ---------------- Pass 3: sum 32 partials per output, apply scale ----------------
__global__ __launch_bounds__(256) void reduce_kernel(
    const float* __restrict__ partial,
    const unsigned* __restrict__ maxbits,
    float* __restrict__ y)
{
    const int o = blockIdx.x * 256 + threadIdx.x;
    float sum = 0.0f;
    #pragma unroll
    for (int p = 0; p < S_SPLIT; ++p)
        sum += partial[(size_t)p * NOUT + o];
    const float maxw = __uint_as_float(*maxbits);
    // y = V_REF / (k_V * k_G) * sum = 0.5/k_G * sum = 0.5*maxw/0.9 * sum
    y[o] = sum * (0.5f * maxw / 0.9f);
}

extern "C" void kernel_launch(void* const* d_in, const int* in_sizes, int n_in,
                              void* d_out, int out_size, void* d_ws, size_t ws_size,
                              hipStream_t stream)
{
    const float* x     = (const float*)d_in[0];
    const float* w_pos = (const float*)d_in[1];
    const float* w_neg = (const float*)d_in[2];
    const float* b_pos = (const float*)d_in[3];
    const float* b_neg = (const float*)d_in[4];
    const float* n_par = (const float*)d_in[5];
    float*    y        = (float*)d_out;

    float*    partial  = (float*)d_ws;                         // 32*65536*4 = 8 MB
    unsigned* maxbits  = (unsigned*)((char*)d_ws + (size_t)S_SPLIT * NOUT * sizeof(float));

    (void)hipMemsetAsync(maxbits, 0, sizeof(unsigned), stream);

    maxabs_kernel<<<256, 256, 0, stream>>>(w_pos, w_neg, b_pos, b_neg, maxbits);

    dim3 grid(NO / TJ, S_SPLIT);
    memristor_main<<<grid, 256, 0, stream>>>(x, w_pos, w_neg, b_pos, b_neg, n_par,
                                             maxbits, partial);

    reduce_kernel<<<NOUT / 256, 256, 0, stream>>>(partial, maxbits, y);
}

// Round 4
// 108.030 us; speedup vs baseline: 1.2193x; 1.2031x over previous
//
#include <hip/hip_runtime.h>

#define NB 64
#define NI 1024
#define NO 1024
#define IROWS (NI + 1)
#define S_SPLIT 32
#define TJ 64
#define NOUT (NB * NO)      // 65536 outputs
#define MAXBLK 256          // blocks in maxabs stage

__device__ __forceinline__ float fast_exp2(float x) { return __builtin_amdgcn_exp2f(x); }
__device__ __forceinline__ float fast_log2(float x) { return __builtin_amdgcn_logf(x); }

// ---- Pass 1: per-block max|W| over {w_pos, w_neg, b_pos, b_neg} -> ws_max[256] ----
__global__ __launch_bounds__(256) void maxabs_stage(
    const float4* __restrict__ wp4, const float4* __restrict__ wn4,
    const float* __restrict__ bp, const float* __restrict__ bn,
    float* __restrict__ ws_max)
{
    const int tid = blockIdx.x * 256 + threadIdx.x;
    const int NW4 = NI * NO / 4;                 // 262144 float4 per matrix
    float m = 0.0f;
    for (int idx = tid; idx < NW4; idx += MAXBLK * 256) {
        float4 a = wp4[idx], b = wn4[idx];
        m = fmaxf(m, fmaxf(fmaxf(fabsf(a.x), fabsf(a.y)), fmaxf(fabsf(a.z), fabsf(a.w))));
        m = fmaxf(m, fmaxf(fmaxf(fabsf(b.x), fabsf(b.y)), fmaxf(fabsf(b.z), fabsf(b.w))));
    }
    if (tid < NO) m = fmaxf(m, fmaxf(fabsf(bp[tid]), fabsf(bn[tid])));

    #pragma unroll
    for (int off = 32; off > 0; off >>= 1)
        m = fmaxf(m, __shfl_xor(m, off));
    __shared__ float wm[4];
    if ((threadIdx.x & 63) == 0) wm[threadIdx.x >> 6] = m;
    __syncthreads();
    if (threadIdx.x == 0)
        ws_max[blockIdx.x] = fmaxf(fmaxf(wm[0], wm[1]), fmaxf(wm[2], wm[3]));
}

// block-wide re-reduction of the 256 partial maxes (cheap, L2-hot)
__device__ __forceinline__ float block_maxw(const float* __restrict__ ws_max, int tid)
{
    float m = ws_max[tid & 255];
    #pragma unroll
    for (int off = 32; off > 0; off >>= 1)
        m = fmaxf(m, __shfl_xor(m, off));
    __shared__ float wm[4];
    if ((tid & 63) == 0) wm[tid >> 6] = m;
    __syncthreads();
    return fmaxf(fmaxf(wm[0], wm[1]), fmaxf(wm[2], wm[3]));
}

// ---- Pass 2: main compute. G folded into exponent: G*r^e = exp2(e*L + log2 G) ----
// Block: 256 thr = 64 j-pairs (tx) x 4 b-groups (ty); thread owns 16 b rows.
// Grid: (NO/TJ) j-tiles x S_SPLIT i-chunks. Partials -> ws.
__global__ __launch_bounds__(256) void memristor_main(
    const float* __restrict__ x,
    const float* __restrict__ w_pos, const float* __restrict__ w_neg,
    const float* __restrict__ b_pos, const float* __restrict__ b_neg,
    const float* __restrict__ n_param,
    const float* __restrict__ ws_max,
    float* __restrict__ partial)
{
    const int tid = threadIdx.x;
    const float maxw = block_maxw(ws_max, tid);
    const float k_G = 0.9f / maxw;

    __shared__ float2 LS[NB][33];   // [b][local_i] : (L = log2(2|x|), sign)

    const int jt = blockIdx.x;
    const int s  = blockIdx.y;
    const int base  = IROWS / S_SPLIT;   // 32
    const int extra = IROWS % S_SPLIT;   // 1
    const int i0  = s * base + min(s, extra);
    const int len = base + (s < extra ? 1 : 0);

    {
        const int li = tid & 63;
        if (li < len) {
            const int gi = i0 + li;
            #pragma unroll 4
            for (int bb = tid >> 6; bb < NB; bb += 4) {
                float v  = (gi < NI) ? x[bb * NI + gi] : 1.0f;   // ones column
                float sg = (v > 0.0f) ? 1.0f : ((v < 0.0f) ? -1.0f : 0.0f);
                float L  = fast_log2(fabsf(v)) + 1.0f;           // log2(2|v|); v=0 -> -inf (ok)
                LS[bb][li] = make_float2(L, sg);
            }
        }
    }
    __syncthreads();

    const int tx = tid & 63;
    const int ty = tid >> 6;
    const int jp = jt * TJ + tx;

    float acc[16];
    #pragma unroll
    for (int k = 0; k < 16; ++k) acc[k] = 0.0f;

    const int reg_len = min(len, NI - i0);
    for (int ii = 0; ii < reg_len; ++ii) {
        const int gi = i0 + ii;
        const float2 n2 = reinterpret_cast<const float2*>(n_param + (size_t)gi * 2 * NO)[jp];
        const float ep   = fast_log2(n2.x);
        const float en   = fast_log2(n2.y);
        const float lgGp = fast_log2(fmaf(k_G, w_pos[gi * NO + jp], 0.1f));  // G>0 guaranteed
        const float lgGn = fast_log2(fmaf(k_G, w_neg[gi * NO + jp], 0.1f));
        #pragma unroll
        for (int k = 0; k < 16; ++k) {
            const float2 ls = LS[ty * 16 + k][ii];    // wave-uniform broadcast
            const float Pp = fast_exp2(fmaf(ep, ls.x, lgGp));
            const float Pn = fast_exp2(fmaf(en, ls.x, lgGn));
            acc[k] = fmaf(ls.y, Pp - Pn, acc[k]);
        }
    }

    if (i0 + len > NI) {   // bias row (gi == NI)
        const int ii = len - 1;
        const float2 n2 = reinterpret_cast<const float2*>(n_param + (size_t)NI * 2 * NO)[jp];
        const float ep   = fast_log2(n2.x);
        const float en   = fast_log2(n2.y);
        const float lgGp = fast_log2(fmaf(k_G, b_pos[jp], 0.1f));
        const float lgGn = fast_log2(fmaf(k_G, b_neg[jp], 0.1f));
        #pragma unroll
        for (int k = 0; k < 16; ++k) {
            const float2 ls = LS[ty * 16 + k][ii];
            const float Pp = fast_exp2(fmaf(ep, ls.x, lgGp));
            const float Pn = fast_exp2(fmaf(en, ls.x, lgGn));
            acc[k] = fmaf(ls.y, Pp - Pn, acc[k]);
        }
    }

    float* slice = partial + (size_t)s * NOUT;
    #pragma unroll
    for (int k = 0; k < 16; ++k)
        slice[(ty * 16 + k) * NO + jp] = acc[k];
}

// ---- Pass 3: sum S_SPLIT partials per output, apply scale ----
__global__ __launch_bounds__(256) void reduce_kernel(
    const float* __restrict__ partial,
    const float* __restrict__ ws_max,
    float* __restrict__ y)
{
    const int tid = threadIdx.x;
    const float maxw = block_maxw(ws_max, tid);
    const int o = blockIdx.x * 256 + tid;
    float sum = 0.0f;
    #pragma unroll
    for (int p = 0; p < S_SPLIT; ++p)
        sum += partial[(size_t)p * NOUT + o];
    // y = V_REF/(k_V*k_G) * sum = 0.5/k_G * sum = 0.5*maxw/0.9 * sum
    y[o] = sum * (0.5f * maxw / 0.9f);
}

extern "C" void kernel_launch(void* const* d_in, const int* in_sizes, int n_in,
                              void* d_out, int out_size, void* d_ws, size_t ws_size,
                              hipStream_t stream)
{
    const float* x     = (const float*)d_in[0];
    const float* w_pos = (const float*)d_in[1];
    const float* w_neg = (const float*)d_in[2];
    const float* b_pos = (const float*)d_in[3];
    const float* b_neg = (const float*)d_in[4];
    const float* n_par = (const float*)d_in[5];
    float*    y        = (float*)d_out;

    float* ws_max  = (float*)d_ws;                       // 256 floats
    float* partial = (float*)d_ws + 1024;                // 32*65536 floats = 8 MB

    maxabs_stage<<<MAXBLK, 256, 0, stream>>>(
        (const float4*)w_pos, (const float4*)w_neg, b_pos, b_neg, ws_max);

    dim3 grid(NO / TJ, S_SPLIT);
    memristor_main<<<grid, 256, 0, stream>>>(x, w_pos, w_neg, b_pos, b_neg, n_par,
                                             ws_max, partial);

    reduce_kernel<<<NOUT / 256, 256, 0, stream>>>(partial, ws_max, y);
}